// Round 1
// baseline (162.517 us; speedup 1.0000x reference)
//
#include <hip/hip_runtime.h>
#include <math.h>

#define DD 32
#define HH 128

// fast tanh: tanh(x) = sign(x) * (1 - e^{-2|x|}) / (1 + e^{-2|x|})
__device__ __forceinline__ float fast_tanh(float x) {
    float ax = fabsf(x);
    float e  = __expf(-2.0f * ax);          // v_exp_f32 path
    float r  = __fdividef(1.0f - e, 1.0f + e);
    return copysignf(r, x);
}

// -------- Kernel 1: dz_dt = tanh([z, t] @ vW1 + vb1) @ vW2 + vb2 ----------
// One thread per row. Weights staged in LDS; vW1 transposed to [HH][36]
// (36-float stride keeps rows 16B-aligned for ds_read_b128; broadcast reads
// are bank-conflict-free regardless).
__global__ __launch_bounds__(256) void k_dzdt(
    const float* __restrict__ t,
    const float* __restrict__ z,
    const float* __restrict__ vW1,   // (33,128) row-major
    const float* __restrict__ vb1,   // (128)
    const float* __restrict__ vW2,   // (128,32) row-major
    const float* __restrict__ vb2,   // (32)
    float* __restrict__ out,
    int B)
{
    __shared__ float sW1t[HH][36];   // sW1t[k][j] = vW1[j][k], j in [0,33)
    __shared__ float sW2[HH][DD];    // row-major copy
    __shared__ float sb1[HH];
    __shared__ float sb2[DD];

    int tid = threadIdx.x;
    for (int i = tid; i < (DD + 1) * HH; i += 256) {
        int j = i / HH, k = i % HH;  // i = j*128 + k
        sW1t[k][j] = vW1[i];
    }
    for (int i = tid; i < HH * DD; i += 256) {
        sW2[i / DD][i % DD] = vW2[i];
    }
    if (tid < HH) sb1[tid] = vb1[tid];
    if (tid < DD) sb2[tid] = vb2[tid];
    __syncthreads();

    int row = blockIdx.x * 256 + tid;
    if (row >= B) return;

    float tval = t[0];

    float zr[DD];
    {
        const float4* zp = (const float4*)(z + (size_t)row * DD);
        #pragma unroll
        for (int q = 0; q < 8; q++) {
            float4 v = zp[q];
            zr[4*q+0] = v.x; zr[4*q+1] = v.y; zr[4*q+2] = v.z; zr[4*q+3] = v.w;
        }
    }

    float acc[DD];
    #pragma unroll
    for (int j = 0; j < DD; j++) acc[j] = sb2[j];

    for (int k = 0; k < HH; k++) {
        const float4* c4 = (const float4*)&sW1t[k][0];
        // u with 4 partial sums to break the dependency chain
        float u0 = sb1[k] + tval * sW1t[k][32];
        float u1 = 0.f, u2 = 0.f, u3 = 0.f;
        #pragma unroll
        for (int q = 0; q < 8; q++) {
            float4 c = c4[q];
            u0 = fmaf(zr[4*q+0], c.x, u0);
            u1 = fmaf(zr[4*q+1], c.y, u1);
            u2 = fmaf(zr[4*q+2], c.z, u2);
            u3 = fmaf(zr[4*q+3], c.w, u3);
        }
        float hk = fast_tanh((u0 + u1) + (u2 + u3));

        const float4* w4 = (const float4*)&sW2[k][0];
        #pragma unroll
        for (int q = 0; q < 8; q++) {
            float4 w = w4[q];
            acc[4*q+0] = fmaf(hk, w.x, acc[4*q+0]);
            acc[4*q+1] = fmaf(hk, w.y, acc[4*q+1]);
            acc[4*q+2] = fmaf(hk, w.z, acc[4*q+2]);
            acc[4*q+3] = fmaf(hk, w.w, acc[4*q+3]);
        }
    }

    float4* op = (float4*)(out + (size_t)row * DD);
    #pragma unroll
    for (int q = 0; q < 8; q++)
        op[q] = make_float4(acc[4*q+0], acc[4*q+1], acc[4*q+2], acc[4*q+3]);
}

// -------- Kernel 2: pair forces (and the 6 off-diagonal triple grads) ------
// g_j(d) = sum_k pW1[j][k] * pW2[k] * (1 - tanh^2(d@pW1 + pb1)_k)
// Pairs: out[a] -= g, out[b] += g  (disjoint rows: perm is a permutation,
// so no atomics needed; stream ordering gives us kernel1's dz_dt in out).
// Triple threads (p >= num_pairs): write raw g to ws for the combine kernel.
__global__ __launch_bounds__(256) void k_force(
    const float* __restrict__ z,
    const int*   __restrict__ perm,
    const float* __restrict__ pW1,   // (32,128) row-major
    const float* __restrict__ pb1,   // (128)
    const float* __restrict__ pW2,   // (128,1)
    float* __restrict__ out,
    float* __restrict__ ws,
    int num_pairs, int nwork)
{
    __shared__ float sW1t[HH][36];   // sW1t[k][j] = pW1[j][k]
    __shared__ float sb1[HH];
    __shared__ float sw2[HH];

    int tid = threadIdx.x;
    for (int i = tid; i < DD * HH; i += 256) {
        int j = i / HH, k = i % HH;
        sW1t[k][j] = pW1[i];
    }
    if (tid < HH) { sb1[tid] = pb1[tid]; sw2[tid] = pW2[tid]; }
    __syncthreads();

    int p = blockIdx.x * 256 + tid;
    if (p >= nwork) return;

    bool is_triple = (p >= num_pairs);
    int tidx = 0, ia, ib;
    if (!is_triple) {
        ia = perm[2 * p];
        ib = perm[2 * p + 1];
    } else {
        tidx = p - num_pairs;            // 0..5 enumerates (i,j), j != i
        int i = tidx >> 1, r = tidx & 1;
        int j = r + ((r >= i) ? 1 : 0);
        ia = perm[2 * num_pairs + i];
        ib = perm[2 * num_pairs + j];
    }

    float diff[DD];
    {
        const float4* za = (const float4*)(z + (size_t)ia * DD);
        const float4* zb = (const float4*)(z + (size_t)ib * DD);
        #pragma unroll
        for (int q = 0; q < 8; q++) {
            float4 A = za[q], Bv = zb[q];
            diff[4*q+0] = A.x - Bv.x;
            diff[4*q+1] = A.y - Bv.y;
            diff[4*q+2] = A.z - Bv.z;
            diff[4*q+3] = A.w - Bv.w;
        }
    }

    float g[DD];
    #pragma unroll
    for (int j = 0; j < DD; j++) g[j] = 0.f;

    for (int k = 0; k < HH; k++) {
        const float4* c4 = (const float4*)&sW1t[k][0];
        float4 c[8];
        #pragma unroll
        for (int q = 0; q < 8; q++) c[q] = c4[q];   // reuse column for both passes

        float u0 = sb1[k], u1 = 0.f, u2 = 0.f, u3 = 0.f;
        #pragma unroll
        for (int q = 0; q < 8; q++) {
            u0 = fmaf(diff[4*q+0], c[q].x, u0);
            u1 = fmaf(diff[4*q+1], c[q].y, u1);
            u2 = fmaf(diff[4*q+2], c[q].z, u2);
            u3 = fmaf(diff[4*q+3], c[q].w, u3);
        }
        float th = fast_tanh((u0 + u1) + (u2 + u3));
        float w  = sw2[k] * (1.0f - th * th);

        #pragma unroll
        for (int q = 0; q < 8; q++) {
            g[4*q+0] = fmaf(w, c[q].x, g[4*q+0]);
            g[4*q+1] = fmaf(w, c[q].y, g[4*q+1]);
            g[4*q+2] = fmaf(w, c[q].z, g[4*q+2]);
            g[4*q+3] = fmaf(w, c[q].w, g[4*q+3]);
        }
    }

    if (!is_triple) {
        float4* oa = (float4*)(out + (size_t)ia * DD);
        float4* ob = (float4*)(out + (size_t)ib * DD);
        #pragma unroll
        for (int q = 0; q < 8; q++) {
            float4 va = oa[q], vb = ob[q];
            va.x -= g[4*q+0]; va.y -= g[4*q+1]; va.z -= g[4*q+2]; va.w -= g[4*q+3];
            vb.x += g[4*q+0]; vb.y += g[4*q+1]; vb.z += g[4*q+2]; vb.w += g[4*q+3];
            oa[q] = va; ob[q] = vb;
        }
    } else {
        float4* wp = (float4*)(ws + (size_t)tidx * DD);
        #pragma unroll
        for (int q = 0; q < 8; q++)
            wp[q] = make_float4(g[4*q+0], g[4*q+1], g[4*q+2], g[4*q+3]);
    }
}

// -------- Kernel 3: deterministic triple combine ---------------------------
// out[perm[p2+i]] += -2 * (g(i,j1) + g(i,j2)), fixed summation order.
__global__ void k_triple_combine(
    const int*   __restrict__ perm,
    const float* __restrict__ ws,
    float* __restrict__ out,
    int num_pairs)
{
    int tid = threadIdx.x;
    if (tid >= 3 * DD) return;
    int i = tid >> 5, d = tid & (DD - 1);
    int row = perm[2 * num_pairs + i];
    float s = ws[(size_t)(2 * i) * DD + d] + ws[(size_t)(2 * i + 1) * DD + d];
    out[(size_t)row * DD + d] -= 2.0f * s;
}

extern "C" void kernel_launch(void* const* d_in, const int* in_sizes, int n_in,
                              void* d_out, int out_size, void* d_ws, size_t ws_size,
                              hipStream_t stream) {
    const float* t    = (const float*)d_in[0];
    const float* z    = (const float*)d_in[1];
    const int*   perm = (const int*)  d_in[2];
    const float* vW1  = (const float*)d_in[3];
    const float* vb1  = (const float*)d_in[4];
    const float* vW2  = (const float*)d_in[5];
    const float* vb2  = (const float*)d_in[6];
    const float* pW1  = (const float*)d_in[7];
    const float* pb1  = (const float*)d_in[8];
    const float* pW2  = (const float*)d_in[9];
    // d_in[10] = pb2: constant, vanishes under grad — unused.

    float* out = (float*)d_out;
    float* ws  = (float*)d_ws;

    int B = in_sizes[2];                 // perm length == batch size
    int num_pairs, num_triples;
    if ((B & 1) == 0) { num_pairs = B / 2;       num_triples = 0; }
    else              { num_pairs = (B - 3) / 2; num_triples = 1; }

    int grid1 = (B + 255) / 256;
    k_dzdt<<<grid1, 256, 0, stream>>>(t, z, vW1, vb1, vW2, vb2, out, B);

    int nwork = num_pairs + (num_triples ? 6 : 0);
    if (nwork > 0) {
        int grid2 = (nwork + 255) / 256;
        k_force<<<grid2, 256, 0, stream>>>(z, perm, pW1, pb1, pW2, out, ws,
                                           num_pairs, nwork);
    }
    if (num_triples) {
        k_triple_combine<<<1, 128, 0, stream>>>(perm, ws, out, num_pairs);
    }
}